// Round 6
// baseline (149.777 us; speedup 1.0000x reference)
//
#include <hip/hip_runtime.h>
#include <hip/hip_bf16.h>

typedef unsigned short u16;
typedef unsigned int u32;
typedef __bf16 bf16x8 __attribute__((ext_vector_type(8)));
typedef float f32x4 __attribute__((ext_vector_type(4)));
typedef unsigned int u32x4 __attribute__((ext_vector_type(4)));
typedef unsigned int u32x2 __attribute__((ext_vector_type(2)));

#define NN 512
#define LL 40
#define DD 128
#define OO 256
#define KK 9
#define MHCL 34
#define TT 32
#define OC 32      // o-chunk width
#define PSTR 136   // pept LDS row stride (u16)
#define MSTR 72    // mhcT LDS row stride (u16)
#define KSTR 136   // kern LDS row stride (u16)
#define LPAD 64    // padded l-dim for MFMA K
#define WPADL 64   // padded l-dim in preconverted W

#define PEPT_U16 (LL * PSTR)   // 5440 u16 = 10880 B
#define KERN_U16 (32 * KSTR)   // 4352 u16 = 8704 B per kern buffer

__device__ __forceinline__ u16 f2bf(float x) {
    unsigned int u = __builtin_bit_cast(unsigned int, x);
    u = (u + 0x7FFFu + ((u >> 16) & 1u)) >> 16;
    return (u16)u;
}
__device__ __forceinline__ u32 pk2(float a, float b) {
    __hip_bfloat162 h = __float22bfloat162_rn(make_float2(a, b)); // x = low half
    u32 r;
    __builtin_memcpy(&r, &h, 4);
    return r;
}
__device__ __forceinline__ bf16x8 lds_read8(const u16* p) {
    u32x4 r;
    __builtin_memcpy(&r, __builtin_assume_aligned(p, 16), 16);
    return __builtin_bit_cast(bf16x8, r);
}
__device__ __forceinline__ f32x4 mfma16(bf16x8 a, bf16x8 b, f32x4 c) {
    return __builtin_amdgcn_mfma_f32_16x16x32_bf16(a, b, c, 0, 0, 0);
}

// prologue: W fp32 [O][K][34] -> bf16 zero-padded [O][K][64] in ws
__global__ void w_convert(const float* __restrict__ wgt, u32* __restrict__ wp) {
    int i = blockIdx.x * 256 + threadIdx.x;        // 36864 u32 outputs
    if (i >= OO * KK * (WPADL / 2)) return;
    int o = i / (KK * (WPADL / 2));
    int r = i - o * (KK * (WPADL / 2));
    int k = r >> 5;
    int lp = (r & 31) << 1;
    const float* src = wgt + ((size_t)o * KK + k) * MHCL;
    float a = (lp     < MHCL) ? src[lp]     : 0.f;
    float b = (lp + 1 < MHCL) ? src[lp + 1] : 0.f;
    wp[i] = pk2(a, b);
}

// R6 = R5 (fused o-chunk pairs) with the epilogue bug fixed: R5 used
// ocS = tid>>8, which IS the group index -> each group only wrote one of its
// two o-chunks (absmax 14.75 = half the output left zeroed). Now each group's
// 256 threads write BOTH chunks (8 floats/thread).
// Theory (untested in R5): per-k-step serial chain has too little independent
// work; fusing two o-chunks doubles filler per latency segment, halves k-steps
// (36->18), barriers, and reduction epilogues. R2 falsified TLP; R4 falsified
// the LDS write->read chain. WRITE_SIZE is the spill tripwire.
template<bool PRE>
__global__ __launch_bounds__(512, 4)
void iconv_kernel(const float* __restrict__ pept,
                  const float* __restrict__ mhc,
                  const float* __restrict__ wgt,
                  const u16* __restrict__ wp,
                  const float* __restrict__ bias,
                  float* __restrict__ out)
{
    // LDS: 10880 + 4*8704 = 45696 B (pept | g0 bufA,bufB | g1 bufA,bufB).
    // mhcT staging [0,18432) overlaps pept+g0 bufs; dead before kern writes.
    // Reduction per pair: red f32[2 oc][2][32][33] = 16896 B over group's two
    // kern bufs (17408 B) after the post-k-loop barrier.
    __shared__ __align__(16) u16 s_mem[PEPT_U16 + 4 * KERN_U16];

    const int tid  = threadIdx.x;
    const int wave = tid >> 6;
    const int grp  = wave >> 2;     // 0: o in [0,128), 1: o in [128,256)
    const int wl   = wave & 3;      // wave-in-group = d-chunk owner
    const int lane = tid & 63;
    const int quad = lane >> 4;
    const int l16  = lane & 15;

    const int n = blockIdx.x;       // 1 block per sample

    u16* const s_pept = s_mem;
    u16* const kbA    = s_mem + PEPT_U16 + grp * (2 * KERN_U16);
    u16* const kbB    = kbA + KERN_U16;

    auto loadW = [&](int o_base, int k, bf16x8 wF[2][2]) {
        if (PRE) {
            #pragma unroll
            for (int mt = 0; mt < 2; ++mt) {
                const u16* wr = wp + ((size_t)(o_base + mt * 16 + l16) * KK + k) * WPADL;
                u32x4 r0, r1;
                __builtin_memcpy(&r0, __builtin_assume_aligned(wr + quad * 8, 16), 16);
                __builtin_memcpy(&r1, __builtin_assume_aligned(wr + 32 + quad * 8, 16), 16);
                wF[mt][0] = __builtin_bit_cast(bf16x8, r0);
                wF[mt][1] = __builtin_bit_cast(bf16x8, r1);
            }
        } else {
            #pragma unroll
            for (int mt = 0; mt < 2; ++mt) {
                const float* wrow = wgt + ((size_t)(o_base + mt * 16 + l16) * KK + k) * MHCL;
                float w8[8];
                __builtin_memcpy(w8, __builtin_assume_aligned(wrow + quad * 8, 8), 32);
                u16 h0[8];
                #pragma unroll
                for (int j = 0; j < 8; ++j) h0[j] = f2bf(w8[j]);
                __builtin_memcpy(&wF[mt][0], h0, 16);
                u16 h1[8] = {0,0,0,0,0,0,0,0};
                if (quad == 0) { h1[0] = f2bf(wrow[32]); h1[1] = f2bf(wrow[33]); }
                __builtin_memcpy(&wF[mt][1], h1, 16);
            }
        }
    };

    // preload k=0 W fragments for the first o-chunk pair: hides under staging
    bf16x8 wA[2][2], wB[2][2];
    loadW(grp * 128, 0, wA);
    loadW(grp * 128 + OC, 0, wB);

    // ---- stage A: mhcT [128][MSTR] bf16, l zero-padded to 64, vectorized b128 writes ----
    {
        const float* mg = mhc + (size_t)n * MHCL * DD;
        #pragma unroll 1
        for (int i = tid; i < DD * (LPAD / 8); i += 512) {   // 1024 items, g wave-uniform
            int g = i >> 7, d = i & 127;
            u32x4 hh;
            #pragma unroll
            for (int jj = 0; jj < 4; ++jj) {
                int l = g * 8 + jj * 2;
                float a = (l     < MHCL) ? mg[(size_t)l * DD + d]       : 0.f;
                float b = (l + 1 < MHCL) ? mg[(size_t)(l + 1) * DD + d] : 0.f;
                hh[jj] = pk2(a, b);
            }
            __builtin_memcpy(__builtin_assume_aligned(&s_mem[d * MSTR + g * 8], 16), &hh, 16);
        }
    }
    __syncthreads();

    // ---- k-invariant mhc A-fragments: group's wave wl owns d in [wl*32, wl*32+32) ----
    bf16x8 aF[2][2];   // [nt-local][ki]; A[m=d][kdim=l]
    #pragma unroll
    for (int ntl = 0; ntl < 2; ++ntl) {
        const int d = (wl * 2 + ntl) * 16 + l16;
        aF[ntl][0] = lds_read8(&s_mem[d * MSTR + quad * 8]);
        aF[ntl][1] = lds_read8(&s_mem[d * MSTR + 32 + quad * 8]);
    }
    __syncthreads();   // mhcT region dead -> pept + kern buffers may overwrite

    // ---- stage B: pept fp32 -> bf16 ----
    {
        const float* pg = pept + (size_t)n * LL * DD;
        #pragma unroll 1
        for (int i = tid; i < (LL * DD) / 4; i += 512) {
            int row = i >> 5, c4 = (i & 31) << 2;
            f32x4 v;
            __builtin_memcpy(&v, __builtin_assume_aligned(pg + row * DD + c4, 16), 16);
            u32x2 h = { pk2(v[0], v[1]), pk2(v[2], v[3]) };
            __builtin_memcpy(__builtin_assume_aligned(&s_pept[row * PSTR + c4], 8), &h, 8);
        }
    }
    __syncthreads();

    // stage1 -> kern buffer kbw: wave computes kern rows (all o') for its own
    // d-columns [32*wl, 32*wl+32) — wave-private column region, no barriers.
    auto stage1 = [&](const bf16x8 wF[2][2], u16* kbw) {
        #pragma unroll
        for (int ntl = 0; ntl < 2; ++ntl) {
            const int nt = wl * 2 + ntl;
            f32x4 c0 = {0.f,0.f,0.f,0.f}, c1 = c0;
            #pragma unroll
            for (int ki = 0; ki < 2; ++ki) {
                c0 = mfma16(aF[ntl][ki], wF[0][ki], c0);   // C[d_local][o' 0..15]
                c1 = mfma16(aF[ntl][ki], wF[1][ki], c1);   // C[d_local][o' 16..31]
            }
            u32x2 p0 = { pk2(fmaxf(c0[0], 0.f), fmaxf(c0[1], 0.f)),
                         pk2(fmaxf(c0[2], 0.f), fmaxf(c0[3], 0.f)) };
            u32x2 p1 = { pk2(fmaxf(c1[0], 0.f), fmaxf(c1[1], 0.f)),
                         pk2(fmaxf(c1[2], 0.f), fmaxf(c1[3], 0.f)) };
            __builtin_memcpy(__builtin_assume_aligned(&kbw[l16 * KSTR + nt * 16 + quad * 4], 8), &p0, 8);
            __builtin_memcpy(__builtin_assume_aligned(&kbw[(16 + l16) * KSTR + nt * 16 + quad * 4], 8), &p1, 8);
        }
    };

    const int off = wl * 32 + quad * 8;   // this wave's d-chunk column offset

    #pragma unroll 1
    for (int oci = 0; oci < 2; ++oci) {
        const int o_baseA = grp * 128 + oci * 64;
        const int o_baseB = o_baseA + OC;
        f32x4 aA00 = {0.f,0.f,0.f,0.f}, aA01 = aA00, aA10 = aA00, aA11 = aA00;
        f32x4 aB00 = aA00, aB01 = aA00, aB10 = aA00, aB11 = aA00;

        // k-loop, fully unrolled. Per step: two independent stage1s fill each
        // other's MFMA->pack latency and the kbA write->read gap; shared pept
        // reads; stage2_A's MFMAs cover kbB's round-trip; W loads for k+1
        // reuse wA/wB registers right after consumption (bounded liveness).
        #pragma unroll
        for (int k = 0; k < KK; ++k) {
            stage1(wA, kbA);
            stage1(wB, kbB);
            if (k < KK - 1) {
                loadW(o_baseA, k + 1, wA);
                loadW(o_baseB, k + 1, wB);
            }
            bf16x8 ap0  = lds_read8(&s_pept[(k + l16) * PSTR + off]);
            bf16x8 ap1  = lds_read8(&s_pept[(k + 16 + l16) * PSTR + off]);
            bf16x8 bkA0 = lds_read8(&kbA[l16 * KSTR + off]);
            bf16x8 bkA1 = lds_read8(&kbA[(16 + l16) * KSTR + off]);
            aA00 = mfma16(ap0, bkA0, aA00);
            aA01 = mfma16(ap0, bkA1, aA01);
            aA10 = mfma16(ap1, bkA0, aA10);
            aA11 = mfma16(ap1, bkA1, aA11);
            bf16x8 bkB0 = lds_read8(&kbB[l16 * KSTR + off]);
            bf16x8 bkB1 = lds_read8(&kbB[(16 + l16) * KSTR + off]);
            aB00 = mfma16(ap0, bkB0, aB00);
            aB01 = mfma16(ap0, bkB1, aB01);
            aB10 = mfma16(ap1, bkB0, aB10);
            aB11 = mfma16(ap1, bkB1, aB11);
        }

        // prefetch next pair's k=0 W fragments: latency hides under reduction
        if (oci == 0) {
            loadW(grp * 128 + 64, 0, wA);
            loadW(grp * 128 + 96, 0, wB);
        }

        __syncthreads();   // kern/stage2 done before red tramples group's bufs
        // ---- cross-wave reduction for BOTH o-chunks: red f32[oc][2][32][33] ----
        float* redA = (float*)kbA;                 // [0, 8448)
        float* redB = redA + 2 * TT * 33;          // [8448, 16896) < 17408
        if (wl < 2) {
            float* rwA = redA + wl * (TT * 33);
            float* rwB = redB + wl * (TT * 33);
            #pragma unroll
            for (int r = 0; r < 4; ++r) {
                rwA[(quad * 4 + r) * 33 + l16]           = aA00[r];
                rwA[(quad * 4 + r) * 33 + 16 + l16]      = aA01[r];
                rwA[(16 + quad * 4 + r) * 33 + l16]      = aA10[r];
                rwA[(16 + quad * 4 + r) * 33 + 16 + l16] = aA11[r];
                rwB[(quad * 4 + r) * 33 + l16]           = aB00[r];
                rwB[(quad * 4 + r) * 33 + 16 + l16]      = aB01[r];
                rwB[(16 + quad * 4 + r) * 33 + l16]      = aB10[r];
                rwB[(16 + quad * 4 + r) * 33 + 16 + l16] = aB11[r];
            }
        }
        __syncthreads();
        if (wl >= 2) {     // disjoint buffers: wl2 -> slot0, wl3 -> slot1
            float* rwA = redA + (wl - 2) * (TT * 33);
            float* rwB = redB + (wl - 2) * (TT * 33);
            #pragma unroll
            for (int r = 0; r < 4; ++r) {
                rwA[(quad * 4 + r) * 33 + l16]           += aA00[r];
                rwA[(quad * 4 + r) * 33 + 16 + l16]      += aA01[r];
                rwA[(16 + quad * 4 + r) * 33 + l16]      += aA10[r];
                rwA[(16 + quad * 4 + r) * 33 + 16 + l16] += aA11[r];
                rwB[(quad * 4 + r) * 33 + l16]           += aB00[r];
                rwB[(quad * 4 + r) * 33 + 16 + l16]      += aB01[r];
                rwB[(16 + quad * 4 + r) * 33 + l16]      += aB10[r];
                rwB[(16 + quad * 4 + r) * 33 + 16 + l16] += aB11[r];
            }
        }
        __syncthreads();

        {   // EPILOGUE FIX: each group's 256 threads write BOTH o-chunks.
            // (R5 bug: ocS = tid>>8 == grp, so half the chunks were never written.)
            const int lt  = tid & 255;      // group-local thread id
            const int o   = lt >> 3;        // 0..31
            const int t0  = (lt & 7) * 4;   // 0,4,...,28
            #pragma unroll
            for (int ocS = 0; ocS < 2; ++ocS) {
                const float* rp = ocS ? redB : redA;
                const int og  = (ocS ? o_baseB : o_baseA) + o;
                const float bv = bias[og];
                f32x4 res;
                #pragma unroll
                for (int j = 0; j < 4; ++j) {
                    int idx = (t0 + j) * 33 + o;
                    res[j] = rp[idx] + rp[TT * 33 + idx] + bv;
                }
                float* op = out + ((size_t)n * OO + og) * TT + t0;
                __builtin_memcpy(__builtin_assume_aligned(op, 16), &res, 16);
            }
        }
        __syncthreads();   // red reads drained before next pair's stage1 writes
    }
}

extern "C" void kernel_launch(void* const* d_in, const int* in_sizes, int n_in,
                              void* d_out, int out_size, void* d_ws, size_t ws_size,
                              hipStream_t stream) {
    const float* pept = (const float*)d_in[0];
    const float* mhc  = (const float*)d_in[1];
    const float* wgt  = (const float*)d_in[2];
    const float* bias = (const float*)d_in[3];
    float* out = (float*)d_out;

    const size_t w_bytes = (size_t)OO * KK * WPADL * sizeof(u16); // 294,912
    if (ws_size >= w_bytes) {
        w_convert<<<dim3((OO * KK * (WPADL / 2) + 255) / 256), dim3(256), 0, stream>>>(wgt, (u32*)d_ws);
        iconv_kernel<true><<<dim3(NN), dim3(512), 0, stream>>>(pept, mhc, wgt, (const u16*)d_ws, bias, out);
    } else {
        iconv_kernel<false><<<dim3(NN), dim3(512), 0, stream>>>(pept, mhc, wgt, nullptr, bias, out);
    }
}

// Round 7
// 117.548 us; speedup vs baseline: 1.2742x; 1.2742x over previous
//
#include <hip/hip_runtime.h>
#include <hip/hip_bf16.h>

typedef unsigned short u16;
typedef unsigned int u32;
typedef __bf16 bf16x8 __attribute__((ext_vector_type(8)));
typedef float f32x4 __attribute__((ext_vector_type(4)));
typedef unsigned int u32x4 __attribute__((ext_vector_type(4)));
typedef unsigned int u32x2 __attribute__((ext_vector_type(2)));

#define NN 512
#define LL 40
#define DD 128
#define OO 256
#define KK 9
#define MHCL 34
#define TT 32
#define PSTR 136   // pept LDS row stride (u16)
#define MSTR 72    // mhcT LDS row stride (u16)
#define KDSTR 72   // kern_s row stride (u16): 64 d + 8 pad
#define LPAD 64    // padded l-dim for MFMA K
#define WPADL 64   // padded l-dim in preconverted W

#define PEPT_U16 (LL * PSTR)    // 5440 u16 = 10880 B
#define KS_U16   (32 * KDSTR)   // 2304 u16 = 4608 B per-wave kern scratch

__device__ __forceinline__ u16 f2bf(float x) {
    unsigned int u = __builtin_bit_cast(unsigned int, x);
    u = (u + 0x7FFFu + ((u >> 16) & 1u)) >> 16;
    return (u16)u;
}
__device__ __forceinline__ u32 pk2(float a, float b) {
    __hip_bfloat162 h = __float22bfloat162_rn(make_float2(a, b)); // x = low half
    u32 r;
    __builtin_memcpy(&r, &h, 4);
    return r;
}
__device__ __forceinline__ bf16x8 lds_read8(const u16* p) {
    u32x4 r;
    __builtin_memcpy(&r, __builtin_assume_aligned(p, 16), 16);
    return __builtin_bit_cast(bf16x8, r);
}
__device__ __forceinline__ f32x4 mfma16(bf16x8 a, bf16x8 b, f32x4 c) {
    return __builtin_amdgcn_mfma_f32_16x16x32_bf16(a, b, c, 0, 0, 0);
}

// prologue: W fp32 [O][K][34] -> bf16 zero-padded [O][K][64] in ws
__global__ void w_convert(const float* __restrict__ wgt, u32* __restrict__ wp) {
    int i = blockIdx.x * 256 + threadIdx.x;        // 36864 u32 outputs
    if (i >= OO * KK * (WPADL / 2)) return;
    int o = i / (KK * (WPADL / 2));
    int r = i - o * (KK * (WPADL / 2));
    int k = r >> 5;
    int lp = (r & 31) << 1;
    const float* src = wgt + ((size_t)o * KK + k) * MHCL;
    float a = (lp     < MHCL) ? src[lp]     : 0.f;
    float b = (lp + 1 < MHCL) ? src[lp + 1] : 0.f;
    wp[i] = pk2(a, b);
}

// R7: LOCKSTEP-BREAKING rewrite. R2/R4/R6 falsified TLP, LDS-RAW latency, and
// per-k ILP width at fixed macro-structure; all variants sit at 80us with all
// pipes <=25% busy, and the sum of observed pipe-busy cycles ~= the wall --
// the 4-wave barrier-resynced lockstep groups collide on the same resource in
// the same phase window. Here each wave owns an (o-chunk, d-half) assignment:
// stage1 kern[32 o'][64 d] -> WAVE-PRIVATE LDS scratch, stage2 consumes it.
// Zero barriers / zero cross-wave deps in the k-loop -> waves drift into
// different phases and their MFMA/VALU/LDS/VMEM demand interleaves. Reduction
// collapses to one pair-wise acc exchange (2 barriers per oc).
template<bool PRE>
__global__ __launch_bounds__(256, 2)
void iconv_kernel(const float* __restrict__ pept,
                  const float* __restrict__ mhc,
                  const float* __restrict__ wgt,
                  const u16* __restrict__ wp,
                  const float* __restrict__ bias,
                  float* __restrict__ out)
{
    // LDS 29312 B: pept[40][136] | 4 x wave-private kern_s[32 o'][72]
    // (kern_s also serves as the pair's acc-exchange buffer in the epilogue).
    // mhcT staging [0,18432) overlaps pept+kern region; dead before any
    // kern write (barriered prologue).
    __shared__ __align__(16) u16 s_mem[PEPT_U16 + 4 * KS_U16];

    const int tid  = threadIdx.x;
    const int wave = tid >> 6;
    const int pair = wave >> 1;     // pair handles o-chunks {base, base+1}
    const int dh   = wave & 1;      // d-half owner: d in [dh*64, dh*64+64)
    const int lane = tid & 63;
    const int quad = lane >> 4;
    const int l16  = lane & 15;

    const int n  = blockIdx.x >> 1;     // 2 blocks per sample
    const int oh = blockIdx.x & 1;      // o-half: chunks [oh*4, oh*4+4)

    u16* const s_pept = s_mem;
    u16* const ks     = s_mem + PEPT_U16 + wave * KS_U16;   // wave-private

    auto loadW = [&](int o_base, int k, bf16x8 wF[2][2]) {
        if (PRE) {
            #pragma unroll
            for (int mt = 0; mt < 2; ++mt) {
                const u16* wr = wp + ((size_t)(o_base + mt * 16 + l16) * KK + k) * WPADL;
                u32x4 r0, r1;
                __builtin_memcpy(&r0, __builtin_assume_aligned(wr + quad * 8, 16), 16);
                __builtin_memcpy(&r1, __builtin_assume_aligned(wr + 32 + quad * 8, 16), 16);
                wF[mt][0] = __builtin_bit_cast(bf16x8, r0);
                wF[mt][1] = __builtin_bit_cast(bf16x8, r1);
            }
        } else {
            #pragma unroll
            for (int mt = 0; mt < 2; ++mt) {
                const float* wrow = wgt + ((size_t)(o_base + mt * 16 + l16) * KK + k) * MHCL;
                float w8[8];
                __builtin_memcpy(w8, __builtin_assume_aligned(wrow + quad * 8, 8), 32);
                u16 h0[8];
                #pragma unroll
                for (int j = 0; j < 8; ++j) h0[j] = f2bf(w8[j]);
                __builtin_memcpy(&wF[mt][0], h0, 16);
                u16 h1[8] = {0,0,0,0,0,0,0,0};
                if (quad == 0) { h1[0] = f2bf(wrow[32]); h1[1] = f2bf(wrow[33]); }
                __builtin_memcpy(&wF[mt][1], h1, 16);
            }
        }
    };

    // first W fragments: global latency hides under staging
    bf16x8 wB[2][2];
    loadW((oh * 4 + pair * 2) * 32, 0, wB);

    // ---- stage A: mhcT [128][MSTR] bf16, l zero-padded to 64 ----
    {
        const float* mg = mhc + (size_t)n * MHCL * DD;
        #pragma unroll 1
        for (int i = tid; i < DD * (LPAD / 8); i += 256) {   // 1024 items
            int g = i >> 7, d = i & 127;
            u32x4 hh;
            #pragma unroll
            for (int jj = 0; jj < 4; ++jj) {
                int l = g * 8 + jj * 2;
                float a = (l     < MHCL) ? mg[(size_t)l * DD + d]       : 0.f;
                float b = (l + 1 < MHCL) ? mg[(size_t)(l + 1) * DD + d] : 0.f;
                hh[jj] = pk2(a, b);
            }
            __builtin_memcpy(__builtin_assume_aligned(&s_mem[d * MSTR + g * 8], 16), &hh, 16);
        }
    }
    __syncthreads();

    // ---- k-invariant mhc A-fragments for this wave's 64 d: 8 frags, 32 VGPR ----
    bf16x8 mA[4][2];   // [d-tile][l-slice]; A[m=d][k=l]
    #pragma unroll
    for (int di = 0; di < 4; ++di) {
        const int d = dh * 64 + di * 16 + l16;
        mA[di][0] = lds_read8(&s_mem[d * MSTR + quad * 8]);
        mA[di][1] = lds_read8(&s_mem[d * MSTR + 32 + quad * 8]);
    }
    __syncthreads();   // mhcT dead -> pept + kern scratches may overwrite

    // ---- stage B: pept fp32 -> bf16 ----
    {
        const float* pg = pept + (size_t)n * LL * DD;
        #pragma unroll 1
        for (int i = tid; i < (LL * DD) / 4; i += 256) {
            int row = i >> 5, c4 = (i & 31) << 2;
            f32x4 v;
            __builtin_memcpy(&v, __builtin_assume_aligned(pg + row * DD + c4, 16), 16);
            u32x2 h = { pk2(v[0], v[1]), pk2(v[2], v[3]) };
            __builtin_memcpy(__builtin_assume_aligned(&s_pept[row * PSTR + c4], 8), &h, 8);
        }
    }
    __syncthreads();

    #pragma unroll 1
    for (int oci = 0; oci < 2; ++oci) {
        const int obase = (oh * 4 + pair * 2 + oci) * 32;
        // acc[ti][oj]: out[t = ti*16 + quad*4 + r][o' = oj*16 + l16], partial over this d-half
        f32x4 acc00 = {0.f,0.f,0.f,0.f}, acc01 = acc00, acc10 = acc00, acc11 = acc00;

        // barrier-free k-loop: all LDS deps are same-wave (private scratch)
        #pragma unroll 3
        for (int k = 0; k < KK; ++k) {
            // stage1: kern[o'=32][d_local=64] for this k -> private scratch
            #pragma unroll
            for (int di = 0; di < 4; ++di) {
                f32x4 c0 = {0.f,0.f,0.f,0.f}, c1 = c0;
                c0 = mfma16(mA[di][0], wB[0][0], c0);   // C[d][o' 0..15]
                c0 = mfma16(mA[di][1], wB[0][1], c0);
                c1 = mfma16(mA[di][0], wB[1][0], c1);   // C[d][o' 16..31]
                c1 = mfma16(mA[di][1], wB[1][1], c1);
                u32x2 p0 = { pk2(fmaxf(c0[0], 0.f), fmaxf(c0[1], 0.f)),
                             pk2(fmaxf(c0[2], 0.f), fmaxf(c0[3], 0.f)) };
                u32x2 p1 = { pk2(fmaxf(c1[0], 0.f), fmaxf(c1[1], 0.f)),
                             pk2(fmaxf(c1[2], 0.f), fmaxf(c1[3], 0.f)) };
                // kern_s[o'][d_local]: lane's 4 C rows are consecutive d
                __builtin_memcpy(__builtin_assume_aligned(&ks[l16 * KDSTR + di * 16 + quad * 4], 8), &p0, 8);
                __builtin_memcpy(__builtin_assume_aligned(&ks[(16 + l16) * KDSTR + di * 16 + quad * 4], 8), &p1, 8);
            }
            // refill wB (fully consumed by stage1 above); latency covered by stage2
            if (k < KK - 1)    loadW(obase, k + 1, wB);
            else if (oci == 0) loadW(obase + 32, 0, wB);
            // stage2: acc += pept[t][d] * kern[d][o'], kdim = 64 in 2 slices
            #pragma unroll
            for (int ds = 0; ds < 2; ++ds) {
                bf16x8 kb0 = lds_read8(&ks[l16 * KDSTR + ds * 32 + quad * 8]);
                bf16x8 kb1 = lds_read8(&ks[(16 + l16) * KDSTR + ds * 32 + quad * 8]);
                bf16x8 ap0 = lds_read8(&s_pept[(k + l16) * PSTR + dh * 64 + ds * 32 + quad * 8]);
                bf16x8 ap1 = lds_read8(&s_pept[(k + 16 + l16) * PSTR + dh * 64 + ds * 32 + quad * 8]);
                acc00 = mfma16(ap0, kb0, acc00);
                acc01 = mfma16(ap0, kb1, acc01);
                acc10 = mfma16(ap1, kb0, acc10);
                acc11 = mfma16(ap1, kb1, acc11);
            }
        }

        // ---- pair reduction: odd wave parks acc in its own scratch; even sums+stores ----
        if (dh == 1) {
            float* ox = (float*)ks;            // 64 lanes x 16 f32 = 4096 B <= 4608
            const int fb = lane * 16;
            __builtin_memcpy(__builtin_assume_aligned(&ox[fb +  0], 16), &acc00, 16);
            __builtin_memcpy(__builtin_assume_aligned(&ox[fb +  4], 16), &acc01, 16);
            __builtin_memcpy(__builtin_assume_aligned(&ox[fb +  8], 16), &acc10, 16);
            __builtin_memcpy(__builtin_assume_aligned(&ox[fb + 12], 16), &acc11, 16);
        }
        __syncthreads();
        if (dh == 0) {
            const float* px = (const float*)(s_mem + PEPT_U16 + (wave + 1) * KS_U16);
            const int fb = lane * 16;
            f32x4 q00, q01, q10, q11;
            __builtin_memcpy(&q00, __builtin_assume_aligned(&px[fb +  0], 16), 16);
            __builtin_memcpy(&q01, __builtin_assume_aligned(&px[fb +  4], 16), 16);
            __builtin_memcpy(&q10, __builtin_assume_aligned(&px[fb +  8], 16), 16);
            __builtin_memcpy(&q11, __builtin_assume_aligned(&px[fb + 12], 16), 16);
            const float bv0 = bias[obase + l16];
            const float bv1 = bias[obase + 16 + l16];
            f32x4 r00 = acc00 + q00 + bv0;
            f32x4 r01 = acc01 + q01 + bv1;
            f32x4 r10 = acc10 + q10 + bv0;
            f32x4 r11 = acc11 + q11 + bv1;
            float* ob = out + ((size_t)n * OO + obase) * TT;
            __builtin_memcpy(__builtin_assume_aligned(ob + (size_t)l16 * TT + quad * 4, 16), &r00, 16);
            __builtin_memcpy(__builtin_assume_aligned(ob + (size_t)(16 + l16) * TT + quad * 4, 16), &r01, 16);
            __builtin_memcpy(__builtin_assume_aligned(ob + (size_t)l16 * TT + 16 + quad * 4, 16), &r10, 16);
            __builtin_memcpy(__builtin_assume_aligned(ob + (size_t)(16 + l16) * TT + 16 + quad * 4, 16), &r11, 16);
        }
        __syncthreads();   // exchange reads drained before next oc's stage1 reuses scratch
    }
}

extern "C" void kernel_launch(void* const* d_in, const int* in_sizes, int n_in,
                              void* d_out, int out_size, void* d_ws, size_t ws_size,
                              hipStream_t stream) {
    const float* pept = (const float*)d_in[0];
    const float* mhc  = (const float*)d_in[1];
    const float* wgt  = (const float*)d_in[2];
    const float* bias = (const float*)d_in[3];
    float* out = (float*)d_out;

    const size_t w_bytes = (size_t)OO * KK * WPADL * sizeof(u16); // 294,912
    if (ws_size >= w_bytes) {
        w_convert<<<dim3((OO * KK * (WPADL / 2) + 255) / 256), dim3(256), 0, stream>>>(wgt, (u32*)d_ws);
        iconv_kernel<true><<<dim3(NN * 2), dim3(256), 0, stream>>>(pept, mhc, wgt, (const u16*)d_ws, bias, out);
    } else {
        iconv_kernel<false><<<dim3(NN * 2), dim3(256), 0, stream>>>(pept, mhc, wgt, nullptr, bias, out);
    }
}